// Round 1
// baseline (828.489 us; speedup 1.0000x reference)
//
#include <hip/hip_runtime.h>

#define N_NODES 50000
#define N_EDGES 800000
#define IN_DIM 128
#define HID 64
#define NUM_GRAPHS 64

__global__ __launch_bounds__(256) void count_kernel(const int* __restrict__ dst, int* __restrict__ degcnt) {
    int e = blockIdx.x * 256 + threadIdx.x;
    if (e < N_EDGES) atomicAdd(&degcnt[dst[e]], 1);
}

__global__ __launch_bounds__(256) void dinv_kernel(const int* __restrict__ degcnt, float* __restrict__ dinv) {
    int n = blockIdx.x * 256 + threadIdx.x;
    if (n < N_NODES) dinv[n] = rsqrtf((float)degcnt[n] + 1.0f);
}

// Single-block exclusive prefix sum over degcnt -> offs[0..N_NODES]
__global__ __launch_bounds__(1024) void scan_kernel(const int* __restrict__ deg, int* __restrict__ offs) {
    __shared__ int wexc[16];
    __shared__ int carry_s;
    int tid = threadIdx.x;
    int lane = tid & 63, wid = tid >> 6;
    if (tid == 0) carry_s = 0;
    __syncthreads();
    for (int base = 0; base < N_NODES; base += 1024) {
        int i = base + tid;
        int v = (i < N_NODES) ? deg[i] : 0;
        int inc = v;
        #pragma unroll
        for (int d = 1; d < 64; d <<= 1) {
            int t = __shfl_up(inc, d, 64);
            if (lane >= d) inc += t;
        }
        if (lane == 63) wexc[wid] = inc;   // inclusive wave totals
        __syncthreads();
        if (tid < 16) {
            int wv = wexc[tid];
            int winc = wv;
            #pragma unroll
            for (int d = 1; d < 16; d <<= 1) {
                int t = __shfl_up(winc, d, 16);
                if (tid >= d) winc += t;
            }
            wexc[tid] = winc - wv;         // exclusive wave offsets
        }
        __syncthreads();
        int excl = carry_s + wexc[wid] + inc - v;
        if (i < N_NODES) offs[i] = excl;
        __syncthreads();
        if (tid == 1023) carry_s += wexc[15] + inc;  // chunk total
        __syncthreads();
    }
    if (tid == 0) offs[N_NODES] = carry_s;
}

__global__ __launch_bounds__(256) void scatter_kernel(const int* __restrict__ src, const int* __restrict__ dst,
                                                      const int* __restrict__ offs, int* __restrict__ cursor,
                                                      const float* __restrict__ dinv,
                                                      int* __restrict__ csr_src, float* __restrict__ csr_nrm) {
    int e = blockIdx.x * 256 + threadIdx.x;
    if (e >= N_EDGES) return;
    int s = src[e], d = dst[e];
    int pos = offs[d] + atomicAdd(&cursor[d], 1);
    csr_src[pos] = s;
    csr_nrm[pos] = dinv[s] * dinv[d];
}

// C = A[nRows,K] @ W[K,64]. Block: 32 nodes x 64 cols, thread = 2 nodes x 4 cols.
template <int K>
__global__ __launch_bounds__(256) void gemm_kernel(const float* __restrict__ A, const float* __restrict__ W,
                                                   float* __restrict__ out, int nRows) {
    constexpr int KP = K + 4;                 // pad: bank stride 4 -> <=2-way conflicts
    __shared__ float xs[32 * KP];
    __shared__ float ws[64 * KP];             // W transposed [c][k]
    int tid = threadIdx.x;
    int node0 = blockIdx.x * 32;
    for (int i = tid; i < K * 64; i += 256) {
        int k = i >> 6, c = i & 63;
        ws[c * KP + k] = W[i];
    }
    for (int i = tid; i < 32 * K; i += 256) {
        int n = i / K, k = i % K;
        int gn = node0 + n;
        xs[n * KP + k] = (gn < nRows) ? A[(size_t)gn * K + k] : 0.0f;
    }
    __syncthreads();
    int tx = tid & 15, ty = tid >> 4;         // tx: col base, ty: node-pair
    int n0 = ty * 2;
    float acc[2][4] = {};
    for (int k = 0; k < K; k += 4) {
        float4 xv[2], wv[4];
        #pragma unroll
        for (int i = 0; i < 2; i++) xv[i] = *(const float4*)&xs[(n0 + i) * KP + k];
        #pragma unroll
        for (int j = 0; j < 4; j++) wv[j] = *(const float4*)&ws[(tx + 16 * j) * KP + k];
        #pragma unroll
        for (int i = 0; i < 2; i++)
            #pragma unroll
            for (int j = 0; j < 4; j++)
                acc[i][j] += xv[i].x * wv[j].x + xv[i].y * wv[j].y + xv[i].z * wv[j].z + xv[i].w * wv[j].w;
    }
    #pragma unroll
    for (int i = 0; i < 2; i++) {
        int gn = node0 + n0 + i;
        if (gn < nRows) {
            #pragma unroll
            for (int j = 0; j < 4; j++) out[(size_t)gn * 64 + tx + 16 * j] = acc[i][j];
        }
    }
}

// agg[n,c] = relu( h[n,c]*dinv[n]^2 + bias[c] + sum_{e: dst=n} h[src,c]*norm[e] )
__global__ __launch_bounds__(256) void agg_kernel(const float* __restrict__ h, const int* __restrict__ offs,
                                                  const int* __restrict__ csr_src, const float* __restrict__ csr_nrm,
                                                  const float* __restrict__ dinv, const float* __restrict__ bias,
                                                  float* __restrict__ out) {
    int c = threadIdx.x & 63;
    int node = blockIdx.x * 4 + (threadIdx.x >> 6);
    if (node >= N_NODES) return;
    float di = dinv[node];
    float acc = h[(size_t)node * 64 + c] * di * di + bias[c];
    int beg = offs[node], end = offs[node + 1];
    for (int j = beg; j < end; j++) {
        int s = csr_src[j];
        float nm = csr_nrm[j];
        acc = fmaf(h[(size_t)s * 64 + c], nm, acc);
    }
    out[(size_t)node * 64 + c] = fmaxf(acc, 0.0f);
}

// per-node dot(y[n,:], Wlin) wave-reduced, atomically segment-summed per graph
__global__ __launch_bounds__(256) void pool_kernel(const float* __restrict__ y, const int* __restrict__ batch,
                                                   const float* __restrict__ Wlin,
                                                   float* __restrict__ gsum, float* __restrict__ gcnt) {
    int lane = threadIdx.x & 63;
    int node = blockIdx.x * 4 + (threadIdx.x >> 6);
    if (node >= N_NODES) return;
    float v = y[(size_t)node * 64 + lane] * Wlin[lane];
    #pragma unroll
    for (int d = 32; d > 0; d >>= 1) v += __shfl_down(v, d, 64);
    if (lane == 0) {
        int g = batch[node];
        atomicAdd(&gsum[g], v);
        atomicAdd(&gcnt[g], 1.0f);
    }
}

__global__ void final_kernel(const float* __restrict__ gsum, const float* __restrict__ gcnt,
                             const float* __restrict__ blin, float* __restrict__ out) {
    int g = threadIdx.x;
    if (g < NUM_GRAPHS) out[g] = gsum[g] / fmaxf(gcnt[g], 1.0f) + blin[0];
}

extern "C" void kernel_launch(void* const* d_in, const int* in_sizes, int n_in,
                              void* d_out, int out_size, void* d_ws, size_t ws_size,
                              hipStream_t stream) {
    const float* x    = (const float*)d_in[0];
    const int*   ei   = (const int*)d_in[1];
    const int*   batch= (const int*)d_in[2];
    const float* W1   = (const float*)d_in[3];
    const float* b1   = (const float*)d_in[4];
    const float* W2   = (const float*)d_in[5];
    const float* b2   = (const float*)d_in[6];
    const float* Wlin = (const float*)d_in[7];
    const float* blin = (const float*)d_in[8];
    float* out = (float*)d_out;
    const int* srcA = ei;
    const int* dstA = ei + N_EDGES;

    char* p = (char*)d_ws;
    auto alloc = [&](size_t n) { char* r = p; p += (n + 255) & ~(size_t)255; return r; };
    int*   degcnt  = (int*)alloc((size_t)N_NODES * 4);
    int*   cursor  = (int*)alloc((size_t)N_NODES * 4);
    float* gsum    = (float*)alloc(NUM_GRAPHS * 4);
    float* gcnt    = (float*)alloc(NUM_GRAPHS * 4);
    size_t zero_bytes = (size_t)(p - (char*)d_ws);
    int*   offs    = (int*)alloc((size_t)(N_NODES + 1) * 4);
    int*   csr_src = (int*)alloc((size_t)N_EDGES * 4);
    float* csr_nrm = (float*)alloc((size_t)N_EDGES * 4);
    float* dinv    = (float*)alloc((size_t)N_NODES * 4);
    float* bufA    = (float*)alloc((size_t)N_NODES * 64 * 4);
    float* bufB    = (float*)alloc((size_t)N_NODES * 64 * 4);

    hipMemsetAsync(d_ws, 0, zero_bytes, stream);

    count_kernel<<<(N_EDGES + 255) / 256, 256, 0, stream>>>(dstA, degcnt);
    dinv_kernel<<<(N_NODES + 255) / 256, 256, 0, stream>>>(degcnt, dinv);
    scan_kernel<<<1, 1024, 0, stream>>>(degcnt, offs);
    scatter_kernel<<<(N_EDGES + 255) / 256, 256, 0, stream>>>(srcA, dstA, offs, cursor, dinv, csr_src, csr_nrm);

    gemm_kernel<IN_DIM><<<(N_NODES + 31) / 32, 256, 0, stream>>>(x, W1, bufA, N_NODES);
    agg_kernel<<<(N_NODES + 3) / 4, 256, 0, stream>>>(bufA, offs, csr_src, csr_nrm, dinv, b1, bufB);
    gemm_kernel<HID><<<(N_NODES + 31) / 32, 256, 0, stream>>>(bufB, W2, bufA, N_NODES);
    agg_kernel<<<(N_NODES + 3) / 4, 256, 0, stream>>>(bufA, offs, csr_src, csr_nrm, dinv, b2, bufB);

    pool_kernel<<<(N_NODES + 3) / 4, 256, 0, stream>>>(bufB, batch, Wlin, gsum, gcnt);
    final_kernel<<<1, 64, 0, stream>>>(gsum, gcnt, blin, out);
}

// Round 2
// 506.866 us; speedup vs baseline: 1.6345x; 1.6345x over previous
//
#include <hip/hip_runtime.h>

#define N_NODES 50000
#define N_EDGES 800000
#define IN_DIM 128
#define HID 64
#define NUM_GRAPHS 64
#define POOL_BLOCKS 128

__global__ __launch_bounds__(256) void count_kernel(const int* __restrict__ dst, int* __restrict__ degcnt) {
    int e = blockIdx.x * 256 + threadIdx.x;
    if (e < N_EDGES) atomicAdd(&degcnt[dst[e]], 1);
}

__global__ __launch_bounds__(256) void dinv_kernel(const int* __restrict__ degcnt, float* __restrict__ dinv) {
    int n = blockIdx.x * 256 + threadIdx.x;
    if (n < N_NODES) dinv[n] = rsqrtf((float)degcnt[n] + 1.0f);
}

// Single-block exclusive prefix sum over degcnt -> offs[0..N_NODES]
__global__ __launch_bounds__(1024) void scan_kernel(const int* __restrict__ deg, int* __restrict__ offs) {
    __shared__ int wexc[16];
    __shared__ int carry_s;
    int tid = threadIdx.x;
    int lane = tid & 63, wid = tid >> 6;
    if (tid == 0) carry_s = 0;
    __syncthreads();
    for (int base = 0; base < N_NODES; base += 1024) {
        int i = base + tid;
        int v = (i < N_NODES) ? deg[i] : 0;
        int inc = v;
        #pragma unroll
        for (int d = 1; d < 64; d <<= 1) {
            int t = __shfl_up(inc, d, 64);
            if (lane >= d) inc += t;
        }
        if (lane == 63) wexc[wid] = inc;   // inclusive wave totals
        __syncthreads();
        if (tid < 16) {
            int wv = wexc[tid];
            int winc = wv;
            #pragma unroll
            for (int d = 1; d < 16; d <<= 1) {
                int t = __shfl_up(winc, d, 16);
                if (tid >= d) winc += t;
            }
            wexc[tid] = winc - wv;         // exclusive wave offsets
        }
        __syncthreads();
        int excl = carry_s + wexc[wid] + inc - v;
        if (i < N_NODES) offs[i] = excl;
        __syncthreads();
        if (tid == 1023) carry_s += wexc[15] + inc;  // chunk total
        __syncthreads();
    }
    if (tid == 0) offs[N_NODES] = carry_s;
}

__global__ __launch_bounds__(256) void scatter_kernel(const int* __restrict__ src, const int* __restrict__ dst,
                                                      const int* __restrict__ offs, int* __restrict__ cursor,
                                                      const float* __restrict__ dinv,
                                                      int* __restrict__ csr_src, float* __restrict__ csr_nrm) {
    int e = blockIdx.x * 256 + threadIdx.x;
    if (e >= N_EDGES) return;
    int s = src[e], d = dst[e];
    int pos = offs[d] + atomicAdd(&cursor[d], 1);
    csr_src[pos] = s;
    csr_nrm[pos] = dinv[s] * dinv[d];
}

// C = A[nRows,K] @ W[K,64]. Block: 32 nodes x 64 cols, thread = 2 nodes x 4 cols.
template <int K>
__global__ __launch_bounds__(256) void gemm_kernel(const float* __restrict__ A, const float* __restrict__ W,
                                                   float* __restrict__ out, int nRows) {
    constexpr int KP = K + 4;                 // pad: bank stride 4 -> <=2-way conflicts
    __shared__ float xs[32 * KP];
    __shared__ float ws[64 * KP];             // W transposed [c][k]
    int tid = threadIdx.x;
    int node0 = blockIdx.x * 32;
    for (int i = tid; i < K * 64; i += 256) {
        int k = i >> 6, c = i & 63;
        ws[c * KP + k] = W[i];
    }
    for (int i = tid; i < 32 * K; i += 256) {
        int n = i / K, k = i % K;
        int gn = node0 + n;
        xs[n * KP + k] = (gn < nRows) ? A[(size_t)gn * K + k] : 0.0f;
    }
    __syncthreads();
    int tx = tid & 15, ty = tid >> 4;         // tx: col base, ty: node-pair
    int n0 = ty * 2;
    float acc[2][4] = {};
    for (int k = 0; k < K; k += 4) {
        float4 xv[2], wv[4];
        #pragma unroll
        for (int i = 0; i < 2; i++) xv[i] = *(const float4*)&xs[(n0 + i) * KP + k];
        #pragma unroll
        for (int j = 0; j < 4; j++) wv[j] = *(const float4*)&ws[(tx + 16 * j) * KP + k];
        #pragma unroll
        for (int i = 0; i < 2; i++)
            #pragma unroll
            for (int j = 0; j < 4; j++)
                acc[i][j] += xv[i].x * wv[j].x + xv[i].y * wv[j].y + xv[i].z * wv[j].z + xv[i].w * wv[j].w;
    }
    #pragma unroll
    for (int i = 0; i < 2; i++) {
        int gn = node0 + n0 + i;
        if (gn < nRows) {
            #pragma unroll
            for (int j = 0; j < 4; j++) out[(size_t)gn * 64 + tx + 16 * j] = acc[i][j];
        }
    }
}

// agg[n,c] = relu( h[n,c]*dinv[n]^2 + bias[c] + sum_{e: dst=n} h[src,c]*norm[e] )
__global__ __launch_bounds__(256) void agg_kernel(const float* __restrict__ h, const int* __restrict__ offs,
                                                  const int* __restrict__ csr_src, const float* __restrict__ csr_nrm,
                                                  const float* __restrict__ dinv, const float* __restrict__ bias,
                                                  float* __restrict__ out) {
    int c = threadIdx.x & 63;
    int node = blockIdx.x * 4 + (threadIdx.x >> 6);
    if (node >= N_NODES) return;
    float di = dinv[node];
    float acc = h[(size_t)node * 64 + c] * di * di + bias[c];
    int beg = offs[node], end = offs[node + 1];
    for (int j = beg; j < end; j++) {
        int s = csr_src[j];
        float nm = csr_nrm[j];
        acc = fmaf(h[(size_t)s * 64 + c], nm, acc);
    }
    out[(size_t)node * 64 + c] = fmaxf(acc, 0.0f);
}

// Two-stage mean-pool+linear: per-block LDS partials -> gpart, no global float atomics.
__global__ __launch_bounds__(256) void pool_kernel(const float* __restrict__ y, const int* __restrict__ batch,
                                                   const float* __restrict__ Wlin,
                                                   float* __restrict__ gpart) {
    __shared__ float lsum[NUM_GRAPHS];
    __shared__ float lcnt[NUM_GRAPHS];
    int tid = threadIdx.x;
    if (tid < NUM_GRAPHS) { lsum[tid] = 0.0f; lcnt[tid] = 0.0f; }
    __syncthreads();
    int lane = tid & 63, wid = tid >> 6;
    float wl = Wlin[lane];
    int stride = gridDim.x * 4;
    for (int node = blockIdx.x * 4 + wid; node < N_NODES; node += stride) {
        float v = y[(size_t)node * 64 + lane] * wl;
        #pragma unroll
        for (int d = 32; d > 0; d >>= 1) v += __shfl_down(v, d, 64);
        if (lane == 0) {
            int g = batch[node];
            atomicAdd(&lsum[g], v);
            atomicAdd(&lcnt[g], 1.0f);
        }
    }
    __syncthreads();
    if (tid < NUM_GRAPHS) {
        gpart[(size_t)blockIdx.x * (2 * NUM_GRAPHS) + tid] = lsum[tid];
        gpart[(size_t)blockIdx.x * (2 * NUM_GRAPHS) + NUM_GRAPHS + tid] = lcnt[tid];
    }
}

__global__ void final_kernel(const float* __restrict__ gpart, const float* __restrict__ blin,
                             float* __restrict__ out) {
    int g = threadIdx.x;
    if (g < NUM_GRAPHS) {
        float s = 0.0f, c = 0.0f;
        for (int b = 0; b < POOL_BLOCKS; b++) {
            s += gpart[(size_t)b * (2 * NUM_GRAPHS) + g];
            c += gpart[(size_t)b * (2 * NUM_GRAPHS) + NUM_GRAPHS + g];
        }
        out[g] = s / fmaxf(c, 1.0f) + blin[0];
    }
}

extern "C" void kernel_launch(void* const* d_in, const int* in_sizes, int n_in,
                              void* d_out, int out_size, void* d_ws, size_t ws_size,
                              hipStream_t stream) {
    const float* x    = (const float*)d_in[0];
    const int*   ei   = (const int*)d_in[1];
    const int*   batch= (const int*)d_in[2];
    const float* W1   = (const float*)d_in[3];
    const float* b1   = (const float*)d_in[4];
    const float* W2   = (const float*)d_in[5];
    const float* b2   = (const float*)d_in[6];
    const float* Wlin = (const float*)d_in[7];
    const float* blin = (const float*)d_in[8];
    float* out = (float*)d_out;
    const int* srcA = ei;
    const int* dstA = ei + N_EDGES;

    char* p = (char*)d_ws;
    auto alloc = [&](size_t n) { char* r = p; p += (n + 255) & ~(size_t)255; return r; };
    int*   degcnt  = (int*)alloc((size_t)N_NODES * 4);
    int*   cursor  = (int*)alloc((size_t)N_NODES * 4);
    size_t zero_bytes = (size_t)(p - (char*)d_ws);
    float* gpart   = (float*)alloc((size_t)POOL_BLOCKS * 2 * NUM_GRAPHS * 4);
    int*   offs    = (int*)alloc((size_t)(N_NODES + 1) * 4);
    int*   csr_src = (int*)alloc((size_t)N_EDGES * 4);
    float* csr_nrm = (float*)alloc((size_t)N_EDGES * 4);
    float* dinv    = (float*)alloc((size_t)N_NODES * 4);
    float* bufA    = (float*)alloc((size_t)N_NODES * 64 * 4);
    float* bufB    = (float*)alloc((size_t)N_NODES * 64 * 4);

    hipMemsetAsync(d_ws, 0, zero_bytes, stream);

    count_kernel<<<(N_EDGES + 255) / 256, 256, 0, stream>>>(dstA, degcnt);
    dinv_kernel<<<(N_NODES + 255) / 256, 256, 0, stream>>>(degcnt, dinv);
    scan_kernel<<<1, 1024, 0, stream>>>(degcnt, offs);
    scatter_kernel<<<(N_EDGES + 255) / 256, 256, 0, stream>>>(srcA, dstA, offs, cursor, dinv, csr_src, csr_nrm);

    gemm_kernel<IN_DIM><<<(N_NODES + 31) / 32, 256, 0, stream>>>(x, W1, bufA, N_NODES);
    agg_kernel<<<(N_NODES + 3) / 4, 256, 0, stream>>>(bufA, offs, csr_src, csr_nrm, dinv, b1, bufB);
    gemm_kernel<HID><<<(N_NODES + 31) / 32, 256, 0, stream>>>(bufB, W2, bufA, N_NODES);
    agg_kernel<<<(N_NODES + 3) / 4, 256, 0, stream>>>(bufA, offs, csr_src, csr_nrm, dinv, b2, bufB);

    pool_kernel<<<POOL_BLOCKS, 256, 0, stream>>>(bufB, batch, Wlin, gpart);
    final_kernel<<<1, 64, 0, stream>>>(gpart, blin, out);
}

// Round 3
// 425.075 us; speedup vs baseline: 1.9490x; 1.1924x over previous
//
#include <hip/hip_runtime.h>

#define N_NODES 50000
#define N_EDGES 800000
#define IN_DIM 128
#define HID 64
#define NUM_GRAPHS 64
#define POOL_BLOCKS 128

__global__ __launch_bounds__(256) void count_kernel(const int* __restrict__ dst, int* __restrict__ degcnt) {
    int e = blockIdx.x * 256 + threadIdx.x;
    if (e < N_EDGES) atomicAdd(&degcnt[dst[e]], 1);
}

__global__ __launch_bounds__(256) void dinv_kernel(const int* __restrict__ degcnt, float* __restrict__ dinv) {
    int n = blockIdx.x * 256 + threadIdx.x;
    if (n < N_NODES) dinv[n] = rsqrtf((float)degcnt[n] + 1.0f);
}

// Single-block scan, chunk-per-thread: ~6 barriers total instead of ~300.
#define SCAN_T 1024
#define CHUNK ((N_NODES + SCAN_T - 1) / SCAN_T)
__global__ __launch_bounds__(SCAN_T) void scan_kernel(const int* __restrict__ deg, int* __restrict__ offs) {
    __shared__ int wsum[16];
    int tid = threadIdx.x;
    int beg = tid * CHUNK;
    int end = beg + CHUNK < N_NODES ? beg + CHUNK : N_NODES;
    int local = 0;
    for (int i = beg; i < end; i++) local += deg[i];
    int lane = tid & 63, wid = tid >> 6;
    int inc = local;
    #pragma unroll
    for (int d = 1; d < 64; d <<= 1) { int t = __shfl_up(inc, d, 64); if (lane >= d) inc += t; }
    if (lane == 63) wsum[wid] = inc;
    __syncthreads();
    if (tid < 16) {
        int wv = wsum[tid], winc = wv;
        #pragma unroll
        for (int d = 1; d < 16; d <<= 1) { int t = __shfl_up(winc, d, 16); if (tid >= d) winc += t; }
        wsum[tid] = winc - wv;
    }
    __syncthreads();
    int run = wsum[wid] + inc - local;     // exclusive prefix at chunk start
    for (int i = beg; i < end; i++) { offs[i] = run; run += deg[i]; }
    if (tid == SCAN_T - 1) offs[N_NODES] = run;
}

// csr[pos] = {src, norm} packed 8B
__global__ __launch_bounds__(256) void scatter_kernel(const int* __restrict__ src, const int* __restrict__ dst,
                                                      const int* __restrict__ offs, int* __restrict__ cursor,
                                                      const float* __restrict__ dinv,
                                                      int2* __restrict__ csr) {
    int e = blockIdx.x * 256 + threadIdx.x;
    if (e >= N_EDGES) return;
    int s = src[e], d = dst[e];
    int pos = offs[d] + atomicAdd(&cursor[d], 1);
    int2 packed;
    packed.x = s;
    packed.y = __float_as_int(dinv[s] * dinv[d]);
    csr[pos] = packed;
}

// C = A[nRows,K] @ W[K,64]. Block: 32 nodes x 64 cols, thread = 2 nodes x 4 cols.
template <int K>
__global__ __launch_bounds__(256) void gemm_kernel(const float* __restrict__ A, const float* __restrict__ W,
                                                   float* __restrict__ out, int nRows) {
    constexpr int KP = K + 4;                 // pad keeps float4 alignment, bank shift 4
    __shared__ float xs[32 * KP];
    __shared__ float ws[64 * KP];             // W transposed [c][k]
    int tid = threadIdx.x;
    int node0 = blockIdx.x * 32;
    // stage W^T: float4 over cols, scalar LDS writes
    for (int i = tid; i < K * 16; i += 256) {
        int k = i >> 4, c4 = (i & 15) * 4;
        float4 wv = *(const float4*)&W[k * 64 + c4];
        ws[(c4 + 0) * KP + k] = wv.x;
        ws[(c4 + 1) * KP + k] = wv.y;
        ws[(c4 + 2) * KP + k] = wv.z;
        ws[(c4 + 3) * KP + k] = wv.w;
    }
    // stage X: float4 loads + float4 LDS writes
    constexpr int K4 = K / 4;
    for (int i = tid; i < 32 * K4; i += 256) {
        int n = i / K4, k4 = i % K4;
        int gn = node0 + n;
        float4 v = (gn < nRows) ? *(const float4*)&A[(size_t)gn * K + k4 * 4]
                                : make_float4(0.f, 0.f, 0.f, 0.f);
        *(float4*)&xs[n * KP + k4 * 4] = v;
    }
    __syncthreads();
    int tx = tid & 15, ty = tid >> 4;
    int n0 = ty * 2;
    float acc[2][4] = {};
    for (int k = 0; k < K; k += 4) {
        float4 xv[2], wv[4];
        #pragma unroll
        for (int i = 0; i < 2; i++) xv[i] = *(const float4*)&xs[(n0 + i) * KP + k];
        #pragma unroll
        for (int j = 0; j < 4; j++) wv[j] = *(const float4*)&ws[(tx + 16 * j) * KP + k];
        #pragma unroll
        for (int i = 0; i < 2; i++)
            #pragma unroll
            for (int j = 0; j < 4; j++)
                acc[i][j] += xv[i].x * wv[j].x + xv[i].y * wv[j].y + xv[i].z * wv[j].z + xv[i].w * wv[j].w;
    }
    #pragma unroll
    for (int i = 0; i < 2; i++) {
        int gn = node0 + n0 + i;
        if (gn < nRows) {
            #pragma unroll
            for (int j = 0; j < 4; j++) out[(size_t)gn * 64 + tx + 16 * j] = acc[i][j];
        }
    }
}

// agg[n,c] = relu( h[n,c]*dinv[n]^2 + bias[c] + sum_{e: dst=n} h[src,c]*norm[e] )
// Wave = 4 quads x 16 lanes; quad q walks edges j=beg+q step 4; lane holds float4 cols.
__global__ __launch_bounds__(256) void agg_kernel(const float* __restrict__ h, const int* __restrict__ offs,
                                                  const int2* __restrict__ csr,
                                                  const float* __restrict__ dinv, const float* __restrict__ bias,
                                                  float* __restrict__ out) {
    int lane = threadIdx.x & 63;
    int node = blockIdx.x * 4 + (threadIdx.x >> 6);
    if (node >= N_NODES) return;
    int q = lane >> 4;
    int cc = (lane & 15) * 4;
    float4 acc = make_float4(0.f, 0.f, 0.f, 0.f);
    int beg = offs[node], end = offs[node + 1];
    #pragma unroll 2
    for (int j = beg + q; j < end; j += 4) {
        int2 e = csr[j];
        float nm = __int_as_float(e.y);
        const float4 hv = *(const float4*)&h[(size_t)e.x * 64 + cc];
        acc.x = fmaf(hv.x, nm, acc.x);
        acc.y = fmaf(hv.y, nm, acc.y);
        acc.z = fmaf(hv.z, nm, acc.z);
        acc.w = fmaf(hv.w, nm, acc.w);
    }
    #pragma unroll
    for (int m = 16; m <= 32; m <<= 1) {
        acc.x += __shfl_xor(acc.x, m, 64);
        acc.y += __shfl_xor(acc.y, m, 64);
        acc.z += __shfl_xor(acc.z, m, 64);
        acc.w += __shfl_xor(acc.w, m, 64);
    }
    if (q == 0) {
        float di = dinv[node];
        float sc = di * di;
        const float4 hn = *(const float4*)&h[(size_t)node * 64 + cc];
        const float4 bv = *(const float4*)&bias[cc];
        float4 r;
        r.x = fmaxf(fmaf(hn.x, sc, bv.x) + acc.x, 0.0f);
        r.y = fmaxf(fmaf(hn.y, sc, bv.y) + acc.y, 0.0f);
        r.z = fmaxf(fmaf(hn.z, sc, bv.z) + acc.z, 0.0f);
        r.w = fmaxf(fmaf(hn.w, sc, bv.w) + acc.w, 0.0f);
        *(float4*)&out[(size_t)node * 64 + cc] = r;
    }
}

// Two-stage mean-pool+linear: per-block LDS partials -> gpart, no global float atomics.
__global__ __launch_bounds__(256) void pool_kernel(const float* __restrict__ y, const int* __restrict__ batch,
                                                   const float* __restrict__ Wlin,
                                                   float* __restrict__ gpart) {
    __shared__ float lsum[NUM_GRAPHS];
    __shared__ float lcnt[NUM_GRAPHS];
    int tid = threadIdx.x;
    if (tid < NUM_GRAPHS) { lsum[tid] = 0.0f; lcnt[tid] = 0.0f; }
    __syncthreads();
    int lane = tid & 63, wid = tid >> 6;
    float wl = Wlin[lane];
    int stride = gridDim.x * 4;
    for (int node = blockIdx.x * 4 + wid; node < N_NODES; node += stride) {
        float v = y[(size_t)node * 64 + lane] * wl;
        #pragma unroll
        for (int d = 32; d > 0; d >>= 1) v += __shfl_down(v, d, 64);
        if (lane == 0) {
            int g = batch[node];
            atomicAdd(&lsum[g], v);
            atomicAdd(&lcnt[g], 1.0f);
        }
    }
    __syncthreads();
    if (tid < NUM_GRAPHS) {
        gpart[(size_t)blockIdx.x * (2 * NUM_GRAPHS) + tid] = lsum[tid];
        gpart[(size_t)blockIdx.x * (2 * NUM_GRAPHS) + NUM_GRAPHS + tid] = lcnt[tid];
    }
}

__global__ void final_kernel(const float* __restrict__ gpart, const float* __restrict__ blin,
                             float* __restrict__ out) {
    int g = threadIdx.x;
    if (g < NUM_GRAPHS) {
        float s = 0.0f, c = 0.0f;
        for (int b = 0; b < POOL_BLOCKS; b++) {
            s += gpart[(size_t)b * (2 * NUM_GRAPHS) + g];
            c += gpart[(size_t)b * (2 * NUM_GRAPHS) + NUM_GRAPHS + g];
        }
        out[g] = s / fmaxf(c, 1.0f) + blin[0];
    }
}

extern "C" void kernel_launch(void* const* d_in, const int* in_sizes, int n_in,
                              void* d_out, int out_size, void* d_ws, size_t ws_size,
                              hipStream_t stream) {
    const float* x    = (const float*)d_in[0];
    const int*   ei   = (const int*)d_in[1];
    const int*   batch= (const int*)d_in[2];
    const float* W1   = (const float*)d_in[3];
    const float* b1   = (const float*)d_in[4];
    const float* W2   = (const float*)d_in[5];
    const float* b2   = (const float*)d_in[6];
    const float* Wlin = (const float*)d_in[7];
    const float* blin = (const float*)d_in[8];
    float* out = (float*)d_out;
    const int* srcA = ei;
    const int* dstA = ei + N_EDGES;

    char* p = (char*)d_ws;
    auto alloc = [&](size_t n) { char* r = p; p += (n + 255) & ~(size_t)255; return r; };
    int*   degcnt  = (int*)alloc((size_t)N_NODES * 4);
    int*   cursor  = (int*)alloc((size_t)N_NODES * 4);
    size_t zero_bytes = (size_t)(p - (char*)d_ws);
    float* gpart   = (float*)alloc((size_t)POOL_BLOCKS * 2 * NUM_GRAPHS * 4);
    int*   offs    = (int*)alloc((size_t)(N_NODES + 1) * 4);
    int2*  csr     = (int2*)alloc((size_t)N_EDGES * 8);
    float* dinv    = (float*)alloc((size_t)N_NODES * 4);
    float* bufA    = (float*)alloc((size_t)N_NODES * 64 * 4);
    float* bufB    = (float*)alloc((size_t)N_NODES * 64 * 4);

    hipMemsetAsync(d_ws, 0, zero_bytes, stream);

    count_kernel<<<(N_EDGES + 255) / 256, 256, 0, stream>>>(dstA, degcnt);
    dinv_kernel<<<(N_NODES + 255) / 256, 256, 0, stream>>>(degcnt, dinv);
    scan_kernel<<<1, SCAN_T, 0, stream>>>(degcnt, offs);
    scatter_kernel<<<(N_EDGES + 255) / 256, 256, 0, stream>>>(srcA, dstA, offs, cursor, dinv, csr);

    gemm_kernel<IN_DIM><<<(N_NODES + 31) / 32, 256, 0, stream>>>(x, W1, bufA, N_NODES);
    agg_kernel<<<(N_NODES + 3) / 4, 256, 0, stream>>>(bufA, offs, csr, dinv, b1, bufB);
    gemm_kernel<HID><<<(N_NODES + 31) / 32, 256, 0, stream>>>(bufB, W2, bufA, N_NODES);
    agg_kernel<<<(N_NODES + 3) / 4, 256, 0, stream>>>(bufA, offs, csr, dinv, b2, bufB);

    pool_kernel<<<POOL_BLOCKS, 256, 0, stream>>>(bufB, batch, Wlin, gpart);
    final_kernel<<<1, 64, 0, stream>>>(gpart, blin, out);
}

// Round 4
// 365.935 us; speedup vs baseline: 2.2640x; 1.1616x over previous
//
#include <hip/hip_runtime.h>

#define N_NODES 50000
#define N_EDGES 800000
#define IN_DIM 128
#define HID 64
#define NUM_GRAPHS 64
#define POOL_BLOCKS 128

__global__ __launch_bounds__(256) void count_kernel(const int* __restrict__ dst, int* __restrict__ degcnt) {
    int e = blockIdx.x * 256 + threadIdx.x;
    if (e < N_EDGES) atomicAdd(&degcnt[dst[e]], 1);
}

__global__ __launch_bounds__(256) void dinv_kernel(const int* __restrict__ degcnt, float* __restrict__ dinv) {
    int n = blockIdx.x * 256 + threadIdx.x;
    if (n < N_NODES) dinv[n] = rsqrtf((float)degcnt[n] + 1.0f);
}

// Single-block scan: tiles of 4096, int4 coalesced loads/stores, 2 barriers/tile.
#define SCAN_T 1024
__global__ __launch_bounds__(SCAN_T) void scan_kernel(const int* __restrict__ deg, int* __restrict__ offs) {
    __shared__ int wsum[16];
    __shared__ int tot_s;
    int tid = threadIdx.x;
    int lane = tid & 63, wid = tid >> 6;
    int carry = 0;
    for (int base = 0; base < N_NODES; base += 4 * SCAN_T) {
        int idx = base + tid * 4;
        int v0 = 0, v1 = 0, v2 = 0, v3 = 0;
        if (idx + 3 < N_NODES) {
            int4 v = *(const int4*)&deg[idx];
            v0 = v.x; v1 = v.y; v2 = v.z; v3 = v.w;
        } else {
            if (idx + 0 < N_NODES) v0 = deg[idx + 0];
            if (idx + 1 < N_NODES) v1 = deg[idx + 1];
            if (idx + 2 < N_NODES) v2 = deg[idx + 2];
            if (idx + 3 < N_NODES) v3 = deg[idx + 3];
        }
        int s0 = v0, s1 = s0 + v1, s2 = s1 + v2, s3 = s2 + v3;  // local inclusive
        int inc = s3;
        #pragma unroll
        for (int d = 1; d < 64; d <<= 1) { int t = __shfl_up(inc, d, 64); if (lane >= d) inc += t; }
        if (lane == 63) wsum[wid] = inc;
        __syncthreads();
        if (tid < 16) {
            int wv = wsum[tid], winc = wv;
            #pragma unroll
            for (int d = 1; d < 16; d <<= 1) { int t = __shfl_up(winc, d, 16); if (tid >= d) winc += t; }
            wsum[tid] = winc - wv;
            if (tid == 15) tot_s = winc;
        }
        __syncthreads();
        int excl = carry + wsum[wid] + inc - s3;
        if (idx + 3 < N_NODES) {
            int4 o; o.x = excl; o.y = excl + s0; o.z = excl + s1; o.w = excl + s2;
            *(int4*)&offs[idx] = o;
        } else {
            if (idx + 0 < N_NODES) offs[idx + 0] = excl;
            if (idx + 1 < N_NODES) offs[idx + 1] = excl + s0;
            if (idx + 2 < N_NODES) offs[idx + 2] = excl + s1;
            if (idx + 3 < N_NODES) offs[idx + 3] = excl + s2;
        }
        carry += tot_s;
        // next tile's wsum writes are ordered by its first __syncthreads()
    }
    if (tid == 0) offs[N_NODES] = carry;
}

// csr[pos] = {src, norm} packed 8B
__global__ __launch_bounds__(256) void scatter_kernel(const int* __restrict__ src, const int* __restrict__ dst,
                                                      const int* __restrict__ offs, int* __restrict__ cursor,
                                                      const float* __restrict__ dinv,
                                                      int2* __restrict__ csr) {
    int e = blockIdx.x * 256 + threadIdx.x;
    if (e >= N_EDGES) return;
    int s = src[e], d = dst[e];
    int pos = offs[d] + atomicAdd(&cursor[d], 1);
    int2 packed;
    packed.x = s;
    packed.y = __float_as_int(dinv[s] * dinv[d]);
    csr[pos] = packed;
}

// C = A[nRows,K] @ W[K,64]. Block: 32 nodes x 64 cols, thread = 2 nodes x 4 cols.
template <int K>
__global__ __launch_bounds__(256) void gemm_kernel(const float* __restrict__ A, const float* __restrict__ W,
                                                   float* __restrict__ out, int nRows) {
    constexpr int KP = K + 4;                 // pad keeps float4 alignment, bank shift 4
    __shared__ float xs[32 * KP];
    __shared__ float ws[64 * KP];             // W transposed [c][k]
    int tid = threadIdx.x;
    int node0 = blockIdx.x * 32;
    for (int i = tid; i < K * 16; i += 256) {
        int k = i >> 4, c4 = (i & 15) * 4;
        float4 wv = *(const float4*)&W[k * 64 + c4];
        ws[(c4 + 0) * KP + k] = wv.x;
        ws[(c4 + 1) * KP + k] = wv.y;
        ws[(c4 + 2) * KP + k] = wv.z;
        ws[(c4 + 3) * KP + k] = wv.w;
    }
    constexpr int K4 = K / 4;
    for (int i = tid; i < 32 * K4; i += 256) {
        int n = i / K4, k4 = i % K4;
        int gn = node0 + n;
        float4 v = (gn < nRows) ? *(const float4*)&A[(size_t)gn * K + k4 * 4]
                                : make_float4(0.f, 0.f, 0.f, 0.f);
        *(float4*)&xs[n * KP + k4 * 4] = v;
    }
    __syncthreads();
    int tx = tid & 15, ty = tid >> 4;
    int n0 = ty * 2;
    float acc[2][4] = {};
    for (int k = 0; k < K; k += 4) {
        float4 xv[2], wv[4];
        #pragma unroll
        for (int i = 0; i < 2; i++) xv[i] = *(const float4*)&xs[(n0 + i) * KP + k];
        #pragma unroll
        for (int j = 0; j < 4; j++) wv[j] = *(const float4*)&ws[(tx + 16 * j) * KP + k];
        #pragma unroll
        for (int i = 0; i < 2; i++)
            #pragma unroll
            for (int j = 0; j < 4; j++)
                acc[i][j] += xv[i].x * wv[j].x + xv[i].y * wv[j].y + xv[i].z * wv[j].z + xv[i].w * wv[j].w;
    }
    #pragma unroll
    for (int i = 0; i < 2; i++) {
        int gn = node0 + n0 + i;
        if (gn < nRows) {
            #pragma unroll
            for (int j = 0; j < 4; j++) out[(size_t)gn * 64 + tx + 16 * j] = acc[i][j];
        }
    }
}

// agg[n,c] = relu( h[n,c]*dinv[n]^2 + bias[c] + sum_{e: dst=n} h[src,c]*norm[e] )
// Wave = 4 quads x 16 lanes; quad q walks edges j=beg+q step 4; lane holds float4 cols.
__global__ __launch_bounds__(256) void agg_kernel(const float* __restrict__ h, const int* __restrict__ offs,
                                                  const int2* __restrict__ csr,
                                                  const float* __restrict__ dinv, const float* __restrict__ bias,
                                                  float* __restrict__ out) {
    int lane = threadIdx.x & 63;
    int node = blockIdx.x * 4 + (threadIdx.x >> 6);
    if (node >= N_NODES) return;
    int q = lane >> 4;
    int cc = (lane & 15) * 4;
    float4 acc = make_float4(0.f, 0.f, 0.f, 0.f);
    int beg = offs[node], end = offs[node + 1];
    #pragma unroll 2
    for (int j = beg + q; j < end; j += 4) {
        int2 e = csr[j];
        float nm = __int_as_float(e.y);
        const float4 hv = *(const float4*)&h[(size_t)e.x * 64 + cc];
        acc.x = fmaf(hv.x, nm, acc.x);
        acc.y = fmaf(hv.y, nm, acc.y);
        acc.z = fmaf(hv.z, nm, acc.z);
        acc.w = fmaf(hv.w, nm, acc.w);
    }
    #pragma unroll
    for (int m = 16; m <= 32; m <<= 1) {
        acc.x += __shfl_xor(acc.x, m, 64);
        acc.y += __shfl_xor(acc.y, m, 64);
        acc.z += __shfl_xor(acc.z, m, 64);
        acc.w += __shfl_xor(acc.w, m, 64);
    }
    if (q == 0) {
        float di = dinv[node];
        float sc = di * di;
        const float4 hn = *(const float4*)&h[(size_t)node * 64 + cc];
        const float4 bv = *(const float4*)&bias[cc];
        float4 r;
        r.x = fmaxf(fmaf(hn.x, sc, bv.x) + acc.x, 0.0f);
        r.y = fmaxf(fmaf(hn.y, sc, bv.y) + acc.y, 0.0f);
        r.z = fmaxf(fmaf(hn.z, sc, bv.z) + acc.z, 0.0f);
        r.w = fmaxf(fmaf(hn.w, sc, bv.w) + acc.w, 0.0f);
        *(float4*)&out[(size_t)node * 64 + cc] = r;
    }
}

// Two-stage mean-pool+linear: per-block LDS partials -> gpart, no global float atomics.
__global__ __launch_bounds__(256) void pool_kernel(const float* __restrict__ y, const int* __restrict__ batch,
                                                   const float* __restrict__ Wlin,
                                                   float* __restrict__ gpart) {
    __shared__ float lsum[NUM_GRAPHS];
    __shared__ float lcnt[NUM_GRAPHS];
    int tid = threadIdx.x;
    if (tid < NUM_GRAPHS) { lsum[tid] = 0.0f; lcnt[tid] = 0.0f; }
    __syncthreads();
    int lane = tid & 63, wid = tid >> 6;
    float wl = Wlin[lane];
    int stride = gridDim.x * 4;
    for (int node = blockIdx.x * 4 + wid; node < N_NODES; node += stride) {
        float v = y[(size_t)node * 64 + lane] * wl;
        #pragma unroll
        for (int d = 32; d > 0; d >>= 1) v += __shfl_down(v, d, 64);
        if (lane == 0) {
            int g = batch[node];
            atomicAdd(&lsum[g], v);
            atomicAdd(&lcnt[g], 1.0f);
        }
    }
    __syncthreads();
    if (tid < NUM_GRAPHS) {
        gpart[(size_t)blockIdx.x * (2 * NUM_GRAPHS) + tid] = lsum[tid];
        gpart[(size_t)blockIdx.x * (2 * NUM_GRAPHS) + NUM_GRAPHS + tid] = lcnt[tid];
    }
}

__global__ void final_kernel(const float* __restrict__ gpart, const float* __restrict__ blin,
                             float* __restrict__ out) {
    int g = threadIdx.x;
    if (g < NUM_GRAPHS) {
        float s = 0.0f, c = 0.0f;
        for (int b = 0; b < POOL_BLOCKS; b++) {
            s += gpart[(size_t)b * (2 * NUM_GRAPHS) + g];
            c += gpart[(size_t)b * (2 * NUM_GRAPHS) + NUM_GRAPHS + g];
        }
        out[g] = s / fmaxf(c, 1.0f) + blin[0];
    }
}

extern "C" void kernel_launch(void* const* d_in, const int* in_sizes, int n_in,
                              void* d_out, int out_size, void* d_ws, size_t ws_size,
                              hipStream_t stream) {
    const float* x    = (const float*)d_in[0];
    const int*   ei   = (const int*)d_in[1];
    const int*   batch= (const int*)d_in[2];
    const float* W1   = (const float*)d_in[3];
    const float* b1   = (const float*)d_in[4];
    const float* W2   = (const float*)d_in[5];
    const float* b2   = (const float*)d_in[6];
    const float* Wlin = (const float*)d_in[7];
    const float* blin = (const float*)d_in[8];
    float* out = (float*)d_out;
    const int* srcA = ei;
    const int* dstA = ei + N_EDGES;

    char* p = (char*)d_ws;
    auto alloc = [&](size_t n) { char* r = p; p += (n + 255) & ~(size_t)255; return r; };
    int*   degcnt  = (int*)alloc((size_t)N_NODES * 4);
    int*   cursor  = (int*)alloc((size_t)N_NODES * 4);
    size_t zero_bytes = (size_t)(p - (char*)d_ws);
    float* gpart   = (float*)alloc((size_t)POOL_BLOCKS * 2 * NUM_GRAPHS * 4);
    int*   offs    = (int*)alloc((size_t)(N_NODES + 1) * 4);
    int2*  csr     = (int2*)alloc((size_t)N_EDGES * 8);
    float* dinv    = (float*)alloc((size_t)N_NODES * 4);
    float* bufA    = (float*)alloc((size_t)N_NODES * 64 * 4);
    float* bufB    = (float*)alloc((size_t)N_NODES * 64 * 4);

    hipMemsetAsync(d_ws, 0, zero_bytes, stream);

    count_kernel<<<(N_EDGES + 255) / 256, 256, 0, stream>>>(dstA, degcnt);
    dinv_kernel<<<(N_NODES + 255) / 256, 256, 0, stream>>>(degcnt, dinv);
    scan_kernel<<<1, SCAN_T, 0, stream>>>(degcnt, offs);
    scatter_kernel<<<(N_EDGES + 255) / 256, 256, 0, stream>>>(srcA, dstA, offs, cursor, dinv, csr);

    gemm_kernel<IN_DIM><<<(N_NODES + 31) / 32, 256, 0, stream>>>(x, W1, bufA, N_NODES);
    agg_kernel<<<(N_NODES + 3) / 4, 256, 0, stream>>>(bufA, offs, csr, dinv, b1, bufB);
    gemm_kernel<HID><<<(N_NODES + 31) / 32, 256, 0, stream>>>(bufB, W2, bufA, N_NODES);
    agg_kernel<<<(N_NODES + 3) / 4, 256, 0, stream>>>(bufA, offs, csr, dinv, b2, bufB);

    pool_kernel<<<POOL_BLOCKS, 256, 0, stream>>>(bufB, batch, Wlin, gpart);
    final_kernel<<<1, 64, 0, stream>>>(gpart, blin, out);
}

// Round 5
// 310.384 us; speedup vs baseline: 2.6692x; 1.1790x over previous
//
#include <hip/hip_runtime.h>

#define N_NODES 50000
#define N_EDGES 800000
#define IN_DIM 128
#define HID 64
#define NUM_GRAPHS 64
#define POOL_BLOCKS 512

__global__ __launch_bounds__(256) void count_kernel(const int* __restrict__ dst, int* __restrict__ degcnt) {
    int e = blockIdx.x * 256 + threadIdx.x;
    if (e < N_EDGES) atomicAdd(&degcnt[dst[e]], 1);
}

__global__ __launch_bounds__(256) void dinv_kernel(const int* __restrict__ degcnt, float* __restrict__ dinv) {
    int n = blockIdx.x * 256 + threadIdx.x;
    if (n < N_NODES) dinv[n] = rsqrtf((float)degcnt[n] + 1.0f);
}

// Single-block scan: tiles of 4096, int4 coalesced loads/stores, 2 barriers/tile.
#define SCAN_T 1024
__global__ __launch_bounds__(SCAN_T) void scan_kernel(const int* __restrict__ deg, int* __restrict__ offs) {
    __shared__ int wsum[16];
    __shared__ int tot_s;
    int tid = threadIdx.x;
    int lane = tid & 63, wid = tid >> 6;
    int carry = 0;
    for (int base = 0; base < N_NODES; base += 4 * SCAN_T) {
        int idx = base + tid * 4;
        int v0 = 0, v1 = 0, v2 = 0, v3 = 0;
        if (idx + 3 < N_NODES) {
            int4 v = *(const int4*)&deg[idx];
            v0 = v.x; v1 = v.y; v2 = v.z; v3 = v.w;
        } else {
            if (idx + 0 < N_NODES) v0 = deg[idx + 0];
            if (idx + 1 < N_NODES) v1 = deg[idx + 1];
            if (idx + 2 < N_NODES) v2 = deg[idx + 2];
            if (idx + 3 < N_NODES) v3 = deg[idx + 3];
        }
        int s0 = v0, s1 = s0 + v1, s2 = s1 + v2, s3 = s2 + v3;  // local inclusive
        int inc = s3;
        #pragma unroll
        for (int d = 1; d < 64; d <<= 1) { int t = __shfl_up(inc, d, 64); if (lane >= d) inc += t; }
        if (lane == 63) wsum[wid] = inc;
        __syncthreads();
        if (tid < 16) {
            int wv = wsum[tid], winc = wv;
            #pragma unroll
            for (int d = 1; d < 16; d <<= 1) { int t = __shfl_up(winc, d, 16); if (tid >= d) winc += t; }
            wsum[tid] = winc - wv;
            if (tid == 15) tot_s = winc;
        }
        __syncthreads();
        int excl = carry + wsum[wid] + inc - s3;
        if (idx + 3 < N_NODES) {
            int4 o; o.x = excl; o.y = excl + s0; o.z = excl + s1; o.w = excl + s2;
            *(int4*)&offs[idx] = o;
        } else {
            if (idx + 0 < N_NODES) offs[idx + 0] = excl;
            if (idx + 1 < N_NODES) offs[idx + 1] = excl + s0;
            if (idx + 2 < N_NODES) offs[idx + 2] = excl + s1;
            if (idx + 3 < N_NODES) offs[idx + 3] = excl + s2;
        }
        carry += tot_s;
    }
    if (tid == 0) offs[N_NODES] = carry;
}

// csr[pos] = {src, norm} packed 8B
__global__ __launch_bounds__(256) void scatter_kernel(const int* __restrict__ src, const int* __restrict__ dst,
                                                      const int* __restrict__ offs, int* __restrict__ cursor,
                                                      const float* __restrict__ dinv,
                                                      int2* __restrict__ csr) {
    int e = blockIdx.x * 256 + threadIdx.x;
    if (e >= N_EDGES) return;
    int s = src[e], d = dst[e];
    int pos = offs[d] + atomicAdd(&cursor[d], 1);
    int2 packed;
    packed.x = s;
    packed.y = __float_as_int(dinv[s] * dinv[d]);
    csr[pos] = packed;
}

// C = A[nRows,K] @ W[K,64]. Block: 32 nodes x 64 cols, thread = 2 nodes x 4 cols.
template <int K>
__global__ __launch_bounds__(256) void gemm_kernel(const float* __restrict__ A, const float* __restrict__ W,
                                                   float* __restrict__ out, int nRows) {
    constexpr int KP = K + 4;                 // pad keeps float4 alignment, bank shift 4
    __shared__ float xs[32 * KP];
    __shared__ float ws[64 * KP];             // W transposed [c][k]
    int tid = threadIdx.x;
    int node0 = blockIdx.x * 32;
    for (int i = tid; i < K * 16; i += 256) {
        int k = i >> 4, c4 = (i & 15) * 4;
        float4 wv = *(const float4*)&W[k * 64 + c4];
        ws[(c4 + 0) * KP + k] = wv.x;
        ws[(c4 + 1) * KP + k] = wv.y;
        ws[(c4 + 2) * KP + k] = wv.z;
        ws[(c4 + 3) * KP + k] = wv.w;
    }
    constexpr int K4 = K / 4;
    for (int i = tid; i < 32 * K4; i += 256) {
        int n = i / K4, k4 = i % K4;
        int gn = node0 + n;
        float4 v = (gn < nRows) ? *(const float4*)&A[(size_t)gn * K + k4 * 4]
                                : make_float4(0.f, 0.f, 0.f, 0.f);
        *(float4*)&xs[n * KP + k4 * 4] = v;
    }
    __syncthreads();
    int tx = tid & 15, ty = tid >> 4;
    int n0 = ty * 2;
    float acc[2][4] = {};
    for (int k = 0; k < K; k += 4) {
        float4 xv[2], wv[4];
        #pragma unroll
        for (int i = 0; i < 2; i++) xv[i] = *(const float4*)&xs[(n0 + i) * KP + k];
        #pragma unroll
        for (int j = 0; j < 4; j++) wv[j] = *(const float4*)&ws[(tx + 16 * j) * KP + k];
        #pragma unroll
        for (int i = 0; i < 2; i++)
            #pragma unroll
            for (int j = 0; j < 4; j++)
                acc[i][j] += xv[i].x * wv[j].x + xv[i].y * wv[j].y + xv[i].z * wv[j].z + xv[i].w * wv[j].w;
    }
    #pragma unroll
    for (int i = 0; i < 2; i++) {
        int gn = node0 + n0 + i;
        if (gn < nRows) {
            #pragma unroll
            for (int j = 0; j < 4; j++) out[(size_t)gn * 64 + tx + 16 * j] = acc[i][j];
        }
    }
}

// agg[n,c] = relu( h[n,c]*dinv[n]^2 + bias[c] + sum_{e: dst=n} h[src,c]*norm[e] )
// Wave = 4 quads x 16 lanes; quad q walks edges j=beg+q step 4; lane holds float4 cols.
__global__ __launch_bounds__(256) void agg_kernel(const float* __restrict__ h, const int* __restrict__ offs,
                                                  const int2* __restrict__ csr,
                                                  const float* __restrict__ dinv, const float* __restrict__ bias,
                                                  float* __restrict__ out) {
    int lane = threadIdx.x & 63;
    int node = blockIdx.x * 4 + (threadIdx.x >> 6);
    if (node >= N_NODES) return;
    int q = lane >> 4;
    int cc = (lane & 15) * 4;
    float4 acc = make_float4(0.f, 0.f, 0.f, 0.f);
    int beg = offs[node], end = offs[node + 1];
    #pragma unroll 2
    for (int j = beg + q; j < end; j += 4) {
        int2 e = csr[j];
        float nm = __int_as_float(e.y);
        const float4 hv = *(const float4*)&h[(size_t)e.x * 64 + cc];
        acc.x = fmaf(hv.x, nm, acc.x);
        acc.y = fmaf(hv.y, nm, acc.y);
        acc.z = fmaf(hv.z, nm, acc.z);
        acc.w = fmaf(hv.w, nm, acc.w);
    }
    #pragma unroll
    for (int m = 16; m <= 32; m <<= 1) {
        acc.x += __shfl_xor(acc.x, m, 64);
        acc.y += __shfl_xor(acc.y, m, 64);
        acc.z += __shfl_xor(acc.z, m, 64);
        acc.w += __shfl_xor(acc.w, m, 64);
    }
    if (q == 0) {
        float di = dinv[node];
        float sc = di * di;
        const float4 hn = *(const float4*)&h[(size_t)node * 64 + cc];
        const float4 bv = *(const float4*)&bias[cc];
        float4 r;
        r.x = fmaxf(fmaf(hn.x, sc, bv.x) + acc.x, 0.0f);
        r.y = fmaxf(fmaf(hn.y, sc, bv.y) + acc.y, 0.0f);
        r.z = fmaxf(fmaf(hn.z, sc, bv.z) + acc.z, 0.0f);
        r.w = fmaxf(fmaf(hn.w, sc, bv.w) + acc.w, 0.0f);
        *(float4*)&out[(size_t)node * 64 + cc] = r;
    }
}

// Pool: wave = 4 quads x 16 lanes; one wave-load covers 4 node rows (1KB).
// Per-block LDS partials -> gpart, no global float atomics.
__global__ __launch_bounds__(256) void pool_kernel(const float* __restrict__ y, const int* __restrict__ batch,
                                                   const float* __restrict__ Wlin,
                                                   float* __restrict__ gpart) {
    __shared__ float lsum[NUM_GRAPHS];
    __shared__ float lcnt[NUM_GRAPHS];
    int tid = threadIdx.x;
    if (tid < NUM_GRAPHS) { lsum[tid] = 0.0f; lcnt[tid] = 0.0f; }
    __syncthreads();
    int lane = tid & 63, wid = tid >> 6;
    int q = lane >> 4;
    int l16 = lane & 15;
    int cc = l16 * 4;
    float4 wl = *(const float4*)&Wlin[cc];
    int stride = gridDim.x * 16;               // 4 waves/block * 4 nodes/wave
    #pragma unroll 2
    for (int node = blockIdx.x * 16 + wid * 4 + q; node < N_NODES; node += stride) {
        const float4 v = *(const float4*)&y[(size_t)node * 64 + cc];
        float d = v.x * wl.x + v.y * wl.y + v.z * wl.z + v.w * wl.w;
        #pragma unroll
        for (int m = 1; m < 16; m <<= 1) d += __shfl_xor(d, m, 64);
        if (l16 == 0) {
            int g = batch[node];
            atomicAdd(&lsum[g], d);
            atomicAdd(&lcnt[g], 1.0f);
        }
    }
    __syncthreads();
    if (tid < NUM_GRAPHS) {
        gpart[(size_t)blockIdx.x * (2 * NUM_GRAPHS) + tid] = lsum[tid];
        gpart[(size_t)blockIdx.x * (2 * NUM_GRAPHS) + NUM_GRAPHS + tid] = lcnt[tid];
    }
}

__global__ __launch_bounds__(1024) void final_kernel(const float* __restrict__ gpart, const float* __restrict__ blin,
                                                     float* __restrict__ out) {
    __shared__ float rs[1024];
    __shared__ float rc[1024];
    int tid = threadIdx.x;
    int g = tid & 63;
    int c = tid >> 6;                          // 16 chunks
    float s = 0.0f, cn = 0.0f;
    for (int b = c; b < POOL_BLOCKS; b += 16) {
        s  += gpart[(size_t)b * (2 * NUM_GRAPHS) + g];
        cn += gpart[(size_t)b * (2 * NUM_GRAPHS) + NUM_GRAPHS + g];
    }
    rs[tid] = s; rc[tid] = cn;
    __syncthreads();
    if (c == 0) {
        float ts = 0.0f, tc = 0.0f;
        #pragma unroll
        for (int k = 0; k < 16; k++) { ts += rs[k * 64 + g]; tc += rc[k * 64 + g]; }
        out[g] = ts / fmaxf(tc, 1.0f) + blin[0];
    }
}

extern "C" void kernel_launch(void* const* d_in, const int* in_sizes, int n_in,
                              void* d_out, int out_size, void* d_ws, size_t ws_size,
                              hipStream_t stream) {
    const float* x    = (const float*)d_in[0];
    const int*   ei   = (const int*)d_in[1];
    const int*   batch= (const int*)d_in[2];
    const float* W1   = (const float*)d_in[3];
    const float* b1   = (const float*)d_in[4];
    const float* W2   = (const float*)d_in[5];
    const float* b2   = (const float*)d_in[6];
    const float* Wlin = (const float*)d_in[7];
    const float* blin = (const float*)d_in[8];
    float* out = (float*)d_out;
    const int* srcA = ei;
    const int* dstA = ei + N_EDGES;

    char* p = (char*)d_ws;
    auto alloc = [&](size_t n) { char* r = p; p += (n + 255) & ~(size_t)255; return r; };
    int*   degcnt  = (int*)alloc((size_t)N_NODES * 4);
    int*   cursor  = (int*)alloc((size_t)N_NODES * 4);
    size_t zero_bytes = (size_t)(p - (char*)d_ws);
    float* gpart   = (float*)alloc((size_t)POOL_BLOCKS * 2 * NUM_GRAPHS * 4);
    int*   offs    = (int*)alloc((size_t)(N_NODES + 1) * 4);
    int2*  csr     = (int2*)alloc((size_t)N_EDGES * 8);
    float* dinv    = (float*)alloc((size_t)N_NODES * 4);
    float* bufA    = (float*)alloc((size_t)N_NODES * 64 * 4);
    float* bufB    = (float*)alloc((size_t)N_NODES * 64 * 4);

    hipMemsetAsync(d_ws, 0, zero_bytes, stream);

    count_kernel<<<(N_EDGES + 255) / 256, 256, 0, stream>>>(dstA, degcnt);
    dinv_kernel<<<(N_NODES + 255) / 256, 256, 0, stream>>>(degcnt, dinv);
    scan_kernel<<<1, SCAN_T, 0, stream>>>(degcnt, offs);
    scatter_kernel<<<(N_EDGES + 255) / 256, 256, 0, stream>>>(srcA, dstA, offs, cursor, dinv, csr);

    gemm_kernel<IN_DIM><<<(N_NODES + 31) / 32, 256, 0, stream>>>(x, W1, bufA, N_NODES);
    agg_kernel<<<(N_NODES + 3) / 4, 256, 0, stream>>>(bufA, offs, csr, dinv, b1, bufB);
    gemm_kernel<HID><<<(N_NODES + 31) / 32, 256, 0, stream>>>(bufB, W2, bufA, N_NODES);
    agg_kernel<<<(N_NODES + 3) / 4, 256, 0, stream>>>(bufA, offs, csr, dinv, b2, bufB);

    pool_kernel<<<POOL_BLOCKS, 256, 0, stream>>>(bufB, batch, Wlin, gpart);
    final_kernel<<<1, 1024, 0, stream>>>(gpart, blin, out);
}